// Round 7
// baseline (171.619 us; speedup 1.0000x reference)
//
#include <hip/hip_runtime.h>
#include <math.h>

// Problem constants (reference: B=4, T=4096, D_MODEL=128, N_HEADS=4, HEAD_DIM=32)
#define B_   4
#define T_   4096
#define DM_  128
#define NH_  4
#define HD_  32
#define TOKENS (B_ * T_)               // 16384

typedef __attribute__((ext_vector_type(8))) short short8;   // 8 bf16 = 4 VGPRs (MFMA A/B frag)
typedef __attribute__((ext_vector_type(4))) float floatx4;  // MFMA C/D frag

__device__ __forceinline__ unsigned short f2bf(float f) {
    union { float f; unsigned int u; } v; v.f = f;
    unsigned int u = v.u;
    u += 0x7fffu + ((u >> 16) & 1u);   // round-to-nearest-even
    return (unsigned short)(u >> 16);
}
__device__ __forceinline__ void split_bf(float v, unsigned short& hi, unsigned short& lo) {
    unsigned short h = f2bf(v);
    float hf = __uint_as_float(((unsigned int)h) << 16);
    hi = h;
    lo = f2bf(v - hf);
}

// -------------------------------------------------------------------------
// Kernel 0: one-time W split -> hi/lo bf16 (row-major, same shape).
// W_qkv: 384x128 = 49152 elems; W_out: 128x128 = 16384 elems.
// -------------------------------------------------------------------------
__global__ __launch_bounds__(256) void w_split_kernel(
    const float* __restrict__ Wqkv, const float* __restrict__ Wout,
    unsigned short* __restrict__ w_hi, unsigned short* __restrict__ w_lo,
    unsigned short* __restrict__ wo_hi, unsigned short* __restrict__ wo_lo)
{
    const int i = blockIdx.x * 256 + threadIdx.x;   // grid 192 blocks -> 49152
    {
        unsigned short h, l;
        split_bf(Wqkv[i], h, l);
        w_hi[i] = h; w_lo[i] = l;
    }
    if (i < DM_ * DM_) {
        unsigned short h, l;
        split_bf(Wout[i], h, l);
        wo_hi[i] = h; wo_lo[i] = l;
    }
}

// -------------------------------------------------------------------------
// Kernel 1: QKV projection via MFMA — LDS-FREE, SYNC-FREE.
// grid (M/64, 6).  A-frags: x fp32 rows -> hi/lo in regs.  B-frags: direct
// 16B bf16 loads from pre-split W (L2-resident).
// Q/K chunks: C = x·W^T.  V chunks: C^T = W·x^T (swapped operands) so
// v_t (bh,32,t) stores are 32B t-segments.
// Outputs: Q bf16 PRE-SCALED by log2(e)/sqrt(32); K bf16; V^T bf16.
// -------------------------------------------------------------------------
__global__ __launch_bounds__(256) void qkv_proj_kernel(
    const float* __restrict__ x,
    const unsigned short* __restrict__ w_hi, const unsigned short* __restrict__ w_lo,
    unsigned short* __restrict__ q_bf, unsigned short* __restrict__ k_bf,
    unsigned short* __restrict__ v_t)
{
    const int tid  = threadIdx.x;
    const int wave = tid >> 6, lane = tid & 63;
    const int m    = lane & 15, q4 = lane >> 4;
    const int m0   = blockIdx.x * 64;
    const int ch   = blockIdx.y;                  // 0..5
    const float scale = 0.2550052509571414f;      // log2(e)/sqrt(32)

    // x frags direct from global: row m0+wave*16+m (serves as A or B)
    short8 Ah[4], Al[4];
    {
        const float4* xg = (const float4*)(x + (size_t)(m0 + wave * 16 + m) * DM_);
        #pragma unroll
        for (int ks = 0; ks < 4; ++ks) {
            float4 a = xg[ks * 8 + q4 * 2];
            float4 b = xg[ks * 8 + q4 * 2 + 1];
            ushort4 h0, l0, h1, l1;
            split_bf(a.x, h0.x, l0.x); split_bf(a.y, h0.y, l0.y);
            split_bf(a.z, h0.z, l0.z); split_bf(a.w, h0.w, l0.w);
            split_bf(b.x, h1.x, l1.x); split_bf(b.y, h1.y, l1.y);
            split_bf(b.z, h1.z, l1.z); split_bf(b.w, h1.w, l1.w);
            Ah[ks] = short8{(short)h0.x, (short)h0.y, (short)h0.z, (short)h0.w,
                            (short)h1.x, (short)h1.y, (short)h1.z, (short)h1.w};
            Al[ks] = short8{(short)l0.x, (short)l0.y, (short)l0.z, (short)l0.w,
                            (short)l1.x, (short)l1.y, (short)l1.z, (short)l1.w};
        }
    }

    const unsigned short* wh = w_hi + (size_t)ch * 64 * DM_;
    const unsigned short* wl = w_lo + (size_t)ch * 64 * DM_;
    const int b    = m0 >> 12;
    const int tloc = (m0 & (T_ - 1)) + wave * 16;

    if (ch < 4) {   // Q (ch 0,1) and K (ch 2,3): C = x·W^T
        #pragma unroll
        for (int nb = 0; nb < 4; ++nb) {
            floatx4 acc = {0.f, 0.f, 0.f, 0.f};
            #pragma unroll
            for (int ks = 0; ks < 4; ++ks) {
                short8 Bh = *(const short8*)(wh + (nb * 16 + m) * DM_ + ks * 32 + q4 * 8);
                short8 Bl = *(const short8*)(wl + (nb * 16 + m) * DM_ + ks * 32 + q4 * 8);
                acc = __builtin_amdgcn_mfma_f32_16x16x32_bf16(Ah[ks], Bh, acc, 0, 0, 0);
                acc = __builtin_amdgcn_mfma_f32_16x16x32_bf16(Ah[ks], Bl, acc, 0, 0, 0);
                acc = __builtin_amdgcn_mfma_f32_16x16x32_bf16(Al[ks], Bh, acc, 0, 0, 0);
            }
            const int n  = ch * 64 + nb * 16 + m;   // col = lane m
            const int hh = (n >> 5) & 3;
            const int d  = n & 31;
            const int bh = b * NH_ + hh;
            const int t0 = tloc + q4 * 4;           // row = q4*4+reg
            if (ch < 2) {
                #pragma unroll
                for (int reg = 0; reg < 4; ++reg)
                    q_bf[((size_t)bh * T_ + t0 + reg) * HD_ + d] = f2bf(acc[reg] * scale);
            } else {
                #pragma unroll
                for (int reg = 0; reg < 4; ++reg)
                    k_bf[((size_t)bh * T_ + t0 + reg) * HD_ + d] = f2bf(acc[reg]);
            }
        }
    } else {        // V (ch 4,5): C^T = W·x^T — rows = W n-index, cols = tokens
        #pragma unroll
        for (int nb = 0; nb < 4; ++nb) {
            floatx4 acc = {0.f, 0.f, 0.f, 0.f};
            #pragma unroll
            for (int ks = 0; ks < 4; ++ks) {
                short8 Bh = *(const short8*)(wh + (nb * 16 + m) * DM_ + ks * 32 + q4 * 8);
                short8 Bl = *(const short8*)(wl + (nb * 16 + m) * DM_ + ks * 32 + q4 * 8);
                acc = __builtin_amdgcn_mfma_f32_16x16x32_bf16(Bh, Ah[ks], acc, 0, 0, 0);
                acc = __builtin_amdgcn_mfma_f32_16x16x32_bf16(Bh, Al[ks], acc, 0, 0, 0);
                acc = __builtin_amdgcn_mfma_f32_16x16x32_bf16(Bl, Ah[ks], acc, 0, 0, 0);
            }
            const int t = tloc + m;                 // col = token (lane m)
            #pragma unroll
            for (int reg = 0; reg < 4; ++reg) {     // row = n local = q4*4+reg
                const int n  = ch * 64 + nb * 16 + q4 * 4 + reg;
                const int hh = (n >> 5) & 3;
                const int d  = n & 31;
                v_t[((size_t)(b * NH_ + hh) * HD_ + d) * T_ + t] = f2bf(acc[reg]);
            }
        }
    }
}

// -------------------------------------------------------------------------
// Kernel 2: bf16 MFMA causal flash attention — R5 structure (known 70 µs).
// S^T = K·Q^T, per-lane scalar stats, P^T packed via v_perm -> 4 b64 LDS
// writes -> PV B-frags.  O^T = V^T·P^T.  exp2-domain softmax.
// CHANGE vs R5: epilogue writes att_hi/att_lo bf16 (hi/lo split of fp32 O).
// -------------------------------------------------------------------------
__global__ __launch_bounds__(256, 4) void attn_mfma_kernel(
    const unsigned short* __restrict__ qb, const unsigned short* __restrict__ kb,
    const unsigned short* __restrict__ vtb,
    unsigned short* __restrict__ att_hi, unsigned short* __restrict__ att_lo)
{
    __shared__ __align__(16) char smem[5120 + 4608 + 4 * 2304];   // 18.5 KB
    char* kLds = smem;             // 64 rows x 80 B  (K tile, (t,d))
    char* vLds = smem + 5120;      // 32 rows x 144 B (V^T tile, (d,t))
    const int tid  = threadIdx.x;
    const int wave = tid >> 6, lane = tid & 63;
    const int m    = lane & 15, q4 = lane >> 4;
    char* pT = smem + 9728 + wave * 2304;   // wave-private P^T: 16 q-rows x 144 B

    // Dispatch swizzle: XCD-locality (2 heads per XCD) + per-CU qt balance.
    const int pid = blockIdx.x;
    const int xcd = pid & 7;
    const int r_  = pid >> 3;
    const int bh  = xcd * 2 + (r_ & 1);
    const int j_  = r_ >> 1;
    const int a_  = j_ & 15, k_ = j_ >> 4;
    const int qt  = (k_ == 0) ? a_ : (k_ == 1) ? 63 - a_
                  : (k_ == 2) ? 32 + a_ : 31 - a_;

    const size_t qkbase = (size_t)bh * T_ * HD_;
    const char* kg = (const char*)(kb + qkbase);
    const char* vg = (const char*)(vtb + qkbase);

    short8 qf = *(const short8*)((const char*)(qb + qkbase)
                 + (size_t)(qt * 64 + wave * 16 + m) * 64 + q4 * 16);
    const int qrow = wave * 16 + m;        // query row within the 64-block

    floatx4 O0 = {0.f, 0.f, 0.f, 0.f}, O1 = {0.f, 0.f, 0.f, 0.f};
    float mx = -INFINITY, ls = 0.f;

    for (int kt = 0; kt <= qt; ++kt) {
        __syncthreads();
        {   // stage K tile (64x64B) + V^T tile (32x128B), split over 256 thr
            const int krow = tid >> 2, ku = tid & 3;
            short8 kv = *(const short8*)(kg + (size_t)(kt * 64 + krow) * 64 + ku * 16);
            const int vd = tid >> 3, vu = tid & 7;
            short8 vv = *(const short8*)(vg + (size_t)vd * (T_ * 2)
                                            + (size_t)kt * 128 + vu * 16);
            *(short8*)(kLds + krow * 80 + ku * 16) = kv;
            *(short8*)(vLds + vd * 144 + vu * 16) = vv;
        }
        __syncthreads();

        // S^T = K·Q^T : C[s=q4*4+reg][q=m]
        floatx4 st[4];
        #pragma unroll
        for (int sb = 0; sb < 4; ++sb) {
            short8 kfrag = *(const short8*)(kLds + (sb * 16 + m) * 80 + q4 * 16);
            floatx4 z = {0.f, 0.f, 0.f, 0.f};
            st[sb] = __builtin_amdgcn_mfma_f32_16x16x32_bf16(kfrag, qf, z, 0, 0, 0);
        }

        if (kt == qt) {   // causal: mask s_local > qrow
            #pragma unroll
            for (int sb = 0; sb < 4; ++sb)
                #pragma unroll
                for (int reg = 0; reg < 4; ++reg)
                    if (sb * 16 + q4 * 4 + reg > qrow) st[sb][reg] = -INFINITY;
        }

        // per-lane row stats over 16 s-values + 2 cross-quad shuffles
        float rmax = -INFINITY;
        #pragma unroll
        for (int sb = 0; sb < 4; ++sb)
            #pragma unroll
            for (int reg = 0; reg < 4; ++reg) rmax = fmaxf(rmax, st[sb][reg]);
        rmax = fmaxf(rmax, __shfl_xor(rmax, 16, 64));
        rmax = fmaxf(rmax, __shfl_xor(rmax, 32, 64));

        const float mn = fmaxf(mx, rmax);
        const float alpha = __builtin_amdgcn_exp2f(mx - mn);   // exp2(-inf)=0 first tile
        mx = mn;

        // p = exp2(s - mn); pack hi16 (round-half-up) via v_perm; 4 b64 writes
        float psum = 0.f;
        #pragma unroll
        for (int sb = 0; sb < 4; ++sb) {
            float p0 = __builtin_amdgcn_exp2f(st[sb][0] - mn);
            float p1 = __builtin_amdgcn_exp2f(st[sb][1] - mn);
            float p2 = __builtin_amdgcn_exp2f(st[sb][2] - mn);
            float p3 = __builtin_amdgcn_exp2f(st[sb][3] - mn);
            psum += (p0 + p1) + (p2 + p3);
            unsigned u0 = __float_as_uint(p0) + 0x8000u;
            unsigned u1 = __float_as_uint(p1) + 0x8000u;
            unsigned u2 = __float_as_uint(p2) + 0x8000u;
            unsigned u3 = __float_as_uint(p3) + 0x8000u;
            uint2 pk;
            pk.x = __builtin_amdgcn_perm(u1, u0, 0x07060302);
            pk.y = __builtin_amdgcn_perm(u3, u2, 0x07060302);
            *(uint2*)(pT + m * 144 + sb * 32 + q4 * 8) = pk;
        }
        psum += __shfl_xor(psum, 16, 64);
        psum += __shfl_xor(psum, 32, 64);
        ls = ls * alpha + psum;
        #pragma unroll
        for (int reg = 0; reg < 4; ++reg) { O0[reg] *= alpha; O1[reg] *= alpha; }

        // drain wave-internal P^T writes before cross-lane B-frag reads
        __asm__ volatile("s_waitcnt lgkmcnt(0)" ::: "memory");

        // O^T += V^T · P^T
        short8 b0  = *(const short8*)(pT + m * 144 + q4 * 16);
        short8 b1  = *(const short8*)(pT + m * 144 + 64 + q4 * 16);
        short8 v00 = *(const short8*)(vLds + m * 144 + q4 * 16);
        short8 v10 = *(const short8*)(vLds + m * 144 + 64 + q4 * 16);
        short8 v01 = *(const short8*)(vLds + (16 + m) * 144 + q4 * 16);
        short8 v11 = *(const short8*)(vLds + (16 + m) * 144 + 64 + q4 * 16);
        O0 = __builtin_amdgcn_mfma_f32_16x16x32_bf16(v00, b0, O0, 0, 0, 0);
        O0 = __builtin_amdgcn_mfma_f32_16x16x32_bf16(v10, b1, O0, 0, 0, 0);
        O1 = __builtin_amdgcn_mfma_f32_16x16x32_bf16(v01, b0, O1, 0, 0, 0);
        O1 = __builtin_amdgcn_mfma_f32_16x16x32_bf16(v11, b1, O1, 0, 0, 0);
    }

    // epilogue: O^T[d][q=m]; write att hi/lo bf16, layout (B,T,H,D)
    const float inv = 1.f / ls;
    const int b = bh >> 2, h = bh & 3;
    const int t = qt * 64 + qrow;
    const size_t rowoff = (((size_t)b * T_ + t) * NH_ + h) * HD_;
    ushort4 h0, l0, h1, l1;
    split_bf(O0[0] * inv, h0.x, l0.x); split_bf(O0[1] * inv, h0.y, l0.y);
    split_bf(O0[2] * inv, h0.z, l0.z); split_bf(O0[3] * inv, h0.w, l0.w);
    split_bf(O1[0] * inv, h1.x, l1.x); split_bf(O1[1] * inv, h1.y, l1.y);
    split_bf(O1[2] * inv, h1.z, l1.z); split_bf(O1[3] * inv, h1.w, l1.w);
    *(ushort4*)(att_hi + rowoff + q4 * 4)      = h0;
    *(ushort4*)(att_hi + rowoff + 16 + q4 * 4) = h1;
    *(ushort4*)(att_lo + rowoff + q4 * 4)      = l0;
    *(ushort4*)(att_lo + rowoff + 16 + q4 * 4) = l1;
}

// -------------------------------------------------------------------------
// Kernel 3: output projection via MFMA — LDS-FREE, SYNC-FREE.
// grid (M/64, 2).  A-frags: direct bf16 loads from att_hi/att_lo.
// B-frags: direct bf16 loads from pre-split Wout.
// -------------------------------------------------------------------------
__global__ __launch_bounds__(256) void out_proj_kernel(
    const unsigned short* __restrict__ att_hi, const unsigned short* __restrict__ att_lo,
    const unsigned short* __restrict__ wo_hi, const unsigned short* __restrict__ wo_lo,
    float* __restrict__ out)
{
    const int tid  = threadIdx.x;
    const int wave = tid >> 6, lane = tid & 63;
    const int m    = lane & 15, q4 = lane >> 4;
    const int m0   = blockIdx.x * 64;
    const int ch   = blockIdx.y;                  // 0..1

    short8 Ah[4], Al[4];
    {
        const size_t row = (size_t)(m0 + wave * 16 + m) * DM_;
        #pragma unroll
        for (int ks = 0; ks < 4; ++ks) {
            Ah[ks] = *(const short8*)(att_hi + row + ks * 32 + q4 * 8);
            Al[ks] = *(const short8*)(att_lo + row + ks * 32 + q4 * 8);
        }
    }

    const unsigned short* wh = wo_hi + (size_t)ch * 64 * DM_;
    const unsigned short* wl = wo_lo + (size_t)ch * 64 * DM_;

    #pragma unroll
    for (int nb = 0; nb < 4; ++nb) {
        floatx4 acc = {0.f, 0.f, 0.f, 0.f};
        #pragma unroll
        for (int ks = 0; ks < 4; ++ks) {
            short8 Bh = *(const short8*)(wh + (nb * 16 + m) * DM_ + ks * 32 + q4 * 8);
            short8 Bl = *(const short8*)(wl + (nb * 16 + m) * DM_ + ks * 32 + q4 * 8);
            acc = __builtin_amdgcn_mfma_f32_16x16x32_bf16(Ah[ks], Bh, acc, 0, 0, 0);
            acc = __builtin_amdgcn_mfma_f32_16x16x32_bf16(Ah[ks], Bl, acc, 0, 0, 0);
            acc = __builtin_amdgcn_mfma_f32_16x16x32_bf16(Al[ks], Bh, acc, 0, 0, 0);
        }
        const int n = ch * 64 + nb * 16 + m;
        const int tok0 = m0 + wave * 16 + q4 * 4;
        #pragma unroll
        for (int reg = 0; reg < 4; ++reg)
            out[(size_t)(tok0 + reg) * DM_ + n] = acc[reg];
    }
}

// -------------------------------------------------------------------------
extern "C" void kernel_launch(void* const* d_in, const int* in_sizes, int n_in,
                              void* d_out, int out_size, void* d_ws, size_t ws_size,
                              hipStream_t stream) {
    const float* x    = (const float*)d_in[0];   // (4,4096,128) fp32
    const float* Wqkv = (const float*)d_in[1];   // (384,128)    fp32
    const float* Wout = (const float*)d_in[2];   // (128,128)    fp32
    float* out = (float*)d_out;                  // (4,4096,128) fp32

    // ws layout (bytes): q_bf 4MB | k_bf 4MB | v_t 4MB | att_hi 4MB | att_lo 4MB
    //                    | w_hi 96KB | w_lo 96KB | wo_hi 32KB | wo_lo 32KB
    char* ws = (char*)d_ws;
    const size_t MB = 1024 * 1024;
    unsigned short* q_bf   = (unsigned short*)(ws);
    unsigned short* k_bf   = (unsigned short*)(ws + 4 * MB);
    unsigned short* v_t    = (unsigned short*)(ws + 8 * MB);
    unsigned short* att_hi = (unsigned short*)(ws + 12 * MB);
    unsigned short* att_lo = (unsigned short*)(ws + 16 * MB);
    unsigned short* w_hi   = (unsigned short*)(ws + 20 * MB);
    unsigned short* w_lo   = (unsigned short*)(ws + 20 * MB + 96 * 1024);
    unsigned short* wo_hi  = (unsigned short*)(ws + 20 * MB + 192 * 1024);
    unsigned short* wo_lo  = (unsigned short*)(ws + 20 * MB + 224 * 1024);

    w_split_kernel<<<192, 256, 0, stream>>>(Wqkv, Wout, w_hi, w_lo, wo_hi, wo_lo);
    qkv_proj_kernel<<<dim3(TOKENS / 64, 6), 256, 0, stream>>>(x, w_hi, w_lo, q_bf, k_bf, v_t);
    attn_mfma_kernel<<<1024, 256, 0, stream>>>(q_bf, k_bf, v_t, att_hi, att_lo);
    out_proj_kernel<<<dim3(TOKENS / 64, 2), 256, 0, stream>>>(att_hi, att_lo, wo_hi, wo_lo, out);
}